// Round 4
// baseline (8024.084 us; speedup 1.0000x reference)
//
#include <hip/hip_runtime.h>
#include <math.h>

#define NBATCH 16
#define DDIM   256
#define TLEN   1500
#define NROWS  (NBATCH * TLEN)     // 24000
#define KBINS  1024
#define NQ     8
#define RPB    32                  // rows per block
#define QMAX   384

typedef float f32x4 __attribute__((ext_vector_type(4)));
typedef int   i32x4 __attribute__((ext_vector_type(4)));
union FragI { uint4 u; i32x4 i; };

// LDS-only barrier: waits ds ops, does NOT drain vmcnt -> global prefetch
// stays in flight across phase boundaries. All inter-wave comms here are LDS.
__device__ __forceinline__ void barrier_lds() {
    __builtin_amdgcn_sched_barrier(0);
    asm volatile("s_waitcnt lgkmcnt(0)" ::: "memory");
    __builtin_amdgcn_s_barrier();
    __builtin_amdgcn_sched_barrier(0);
}

// quantize 4 floats to 4 i8 (round-nearest-even), accumulate exact eps^2
__device__ __forceinline__ unsigned pack8(float4 v, float inv, float s, float& e2) {
    float q0 = rintf(v.x * inv), q1 = rintf(v.y * inv);
    float q2 = rintf(v.z * inv), q3 = rintf(v.w * inv);
    float e0 = __builtin_fmaf(-s, q0, v.x), e1 = __builtin_fmaf(-s, q1, v.y);
    float f2 = __builtin_fmaf(-s, q2, v.z), f3 = __builtin_fmaf(-s, q3, v.w);
    e2 += e0 * e0 + e1 * e1 + f2 * f2 + f3 * f3;
    return ((unsigned)((int)q0 & 255)) | (((unsigned)((int)q1 & 255)) << 8)
         | (((unsigned)((int)q2 & 255)) << 16) | (((unsigned)((int)q3 & 255)) << 24);
}

// ---------------------------------------------------------------------------
// Kernel 1: per-col table: (cbsq numpy-pairwise, sB, ||eps_b||, ||c||) + zero losses
// ---------------------------------------------------------------------------
__global__ __launch_bounds__(256) void table_kernel(const float* __restrict__ cb,
                                                    float* __restrict__ ws) {
    const int k = blockIdx.x * 256 + threadIdx.x;      // 0..8191
    if (blockIdx.x == 0 && threadIdx.x < NQ) ws[4 * NQ * KBINS + threadIdx.x] = 0.f;
    if (k >= NQ * KBINS) return;
    const float* p = cb + (size_t)k * DDIM;
    // numpy-pairwise sum(c*c) -- EXACT structure as the passing kernel
    float total = 0.f;
    #pragma unroll
    for (int h = 0; h < 2; ++h) {
        const float* ph = p + h * 128;
        float r[8];
        #pragma unroll
        for (int j = 0; j < 8; ++j) { float v = ph[j]; r[j] = __fmul_rn(v, v); }
        for (int i = 8; i < 128; i += 8) {
            #pragma unroll
            for (int j = 0; j < 8; ++j) {
                float v = ph[i + j];
                r[j] = __fadd_rn(r[j], __fmul_rn(v, v));
            }
        }
        float s = __fadd_rn(__fadd_rn(__fadd_rn(r[0], r[1]), __fadd_rn(r[2], r[3])),
                            __fadd_rn(__fadd_rn(r[4], r[5]), __fadd_rn(r[6], r[7])));
        total = __fadd_rn(total, s);
    }
    // maxabs -> sB; exact quantization error norm
    float ma = 0.f;
    for (int i = 0; i < DDIM; i += 4) {
        float4 v = *(const float4*)(p + i);
        ma = fmaxf(ma, fmaxf(fmaxf(fabsf(v.x), fabsf(v.y)), fmaxf(fabsf(v.z), fabsf(v.w))));
    }
    const float sB = fmaxf(ma, 1e-30f) * (1.f / 127.f);
    const float invB = 1.f / sB;
    float es = 0.f;
    for (int i = 0; i < DDIM; i += 4) {
        float4 v = *(const float4*)(p + i);
        (void)pack8(v, invB, sB, es);
    }
    float4 t;
    t.x = total; t.y = sB; t.z = sqrtf(es); t.w = sqrtf(total);
    ((float4*)ws)[k] = t;
}

// ---------------------------------------------------------------------------
// Kernel 1b: pre-quantize codebooks fp32 -> i8 in per-lane MFMA fragment order
// uint4 index J = ((((q*16+ch)*4 + w)*4 + ks)*64 + l); byte p of lane l:
// col = ch*64 + w*16 + (l&15), k = ks*64 + (l>>4)*16 + p  (A uses same k map)
// ---------------------------------------------------------------------------
__global__ __launch_bounds__(256) void precvt8_kernel(const float* __restrict__ cb,
                                                      const float4* __restrict__ tab,
                                                      uint4* __restrict__ cbbf) {
    const int j = blockIdx.x * 256 + threadIdx.x;      // < 131072
    const int l  = j & 63;
    const int ks = (j >> 6) & 3;
    const int w  = (j >> 8) & 3;
    const int ch = (j >> 10) & 15;
    const int q  = j >> 14;
    const int C  = ch * 64 + w * 16 + (l & 15);
    const int g  = l >> 4;
    const float* src = cb + ((size_t)q * KBINS + C) * DDIM + ks * 64 + g * 16;
    const float sB = tab[q * KBINS + C].y;
    const float invB = 1.f / sB;
    float dummy = 0.f;
    uint4 o;
    o.x = pack8(*(const float4*)(src + 0),  invB, sB, dummy);
    o.y = pack8(*(const float4*)(src + 4),  invB, sB, dummy);
    o.z = pack8(*(const float4*)(src + 8),  invB, sB, dummy);
    o.w = pack8(*(const float4*)(src + 12), invB, sB, dummy);
    cbbf[j] = o;
}

// ---------------------------------------------------------------------------
// Kernel 2: residual VQ. i8-MFMA screening (exact int dot; provable quant
// margin from measured ||eps_a||,||eps_b||), register-double-buffered B,
// LDS-only barriers, global cross-wave row-max thresholds, exact fp32
// rescoring with overflow repair pass. i8 halves B regs+traffic: demand
// ~140 regs -> launch_bounds(256,3) -> 3 waves/SIMD.
// ---------------------------------------------------------------------------
template<bool WSCB>
__global__ __launch_bounds__(256, 3) void rvq_kernel(const float* __restrict__ x,
                                                     const float* __restrict__ cb,
                                                     const uint4* __restrict__ cbbf,
                                                     const float4* __restrict__ tab,
                                                     float* __restrict__ loss,
                                                     float* __restrict__ out) {
    __shared__ __align__(16) float As[RPB][260];       // residual fp32 (33.3KB)
    __shared__ float rsq[RPB];
    __shared__ unsigned maxa_s[RPB];                   // row maxabs (fabs bits)
    __shared__ float ean_s[RPB];                       // row ||eps_a||
    __shared__ float Mrow_s[RPB];
    __shared__ float Mpart[2][4][RPB];                 // parity-buffered (1KB)
    __shared__ unsigned long long winner[RPB];
    __shared__ int   idxs[RPB];
    __shared__ int   qlist[QMAX];                      // 1.5KB
    __shared__ int   qcnt;
    __shared__ unsigned ovf;                           // rows whose cands overflowed
    __shared__ float redE[4], redC[4];

    const int tid = threadIdx.x;
    const int r0  = blockIdx.x * RPB;
    const int w   = tid >> 6;          // wave 0..3
    const int l   = tid & 63;
    const int cl  = l & 15;
    const int g   = l >> 4;            // 0..3

    if (tid < RPB) { rsq[tid] = 0.f; maxa_s[tid] = 0u; }
    barrier_lds();

    // ---- load x (B,D,T) transposed into As[row][d]; ||r||^2 and maxabs ----
    {
        const int row = tid & 31, dg = tid >> 5;
        const int n = r0 + row, b = n / TLEN, t = n % TLEN;
        const float* xp = x + (size_t)b * (DDIM * TLEN) + t;
        float pr = 0.f, ma = 0.f;
        #pragma unroll
        for (int dd = 0; dd < DDIM; dd += 8) {
            float v = xp[(size_t)(dd + dg) * TLEN];
            As[row][dd + dg] = v;
            pr = __builtin_fmaf(v, v, pr);
            ma = fmaxf(ma, fabsf(v));
        }
        atomicAdd(&rsq[row], pr);
        atomicMax(&maxa_s[row], __float_as_uint(ma));
    }
    barrier_lds();

    float* codes_f = out + (size_t)NBATCH * DDIM * TLEN;

    // B-fragment loader: 4 coalesced dwordx4 per chunk (i8, K=64 each)
    auto loadB = [&](uint4 (&buf)[4], int q_, int ch_) {
        if constexpr (WSCB) {
            const uint4* p = cbbf + ((size_t)((q_ * 16 + ch_) * 4 + w) * 4) * 64 + l;
            #pragma unroll
            for (int ks = 0; ks < 4; ++ks) buf[ks] = p[ks * 64];
        } else {
            const int C = ch_ * 64 + w * 16 + cl;
            const float* cp = cb + ((size_t)q_ * KBINS + C) * DDIM;
            const float sB = tab[q_ * KBINS + C].y;
            const float invB = 1.f / sB;
            float dmy = 0.f;
            #pragma unroll
            for (int ks = 0; ks < 4; ++ks) {
                const int d0 = ks * 64 + g * 16;
                buf[ks].x = pack8(*(const float4*)(cp + d0 + 0),  invB, sB, dmy);
                buf[ks].y = pack8(*(const float4*)(cp + d0 + 4),  invB, sB, dmy);
                buf[ks].z = pack8(*(const float4*)(cp + d0 + 8),  invB, sB, dmy);
                buf[ks].w = pack8(*(const float4*)(cp + d0 + 12), invB, sB, dmy);
            }
        }
    };
    auto loadT = [&](int q_, int ch_) -> float4 {
        return tab[q_ * KBINS + ch_ * 64 + w * 16 + cl];
    };

    uint4 bufA[4], bufB[4];
    float4 tA, tB;
    loadB(bufA, 0, 0);                 // prologue: stage 0 chunk 0 in flight
    tA = loadT(0, 0);
    __builtin_amdgcn_sched_barrier(0);

    for (int q = 0; q < NQ; ++q) {
        const float* cbq = cb + (size_t)q * (KBINS * DDIM);
        const float4* tabq = tab + (size_t)q * KBINS;

        // exact fp32 score of (row,col) -> tournament key -> atomicMax winner
        auto exact_score = [&](int row, int col) {
            const float* cp = cbq + (size_t)col * DDIM;
            const float* ar = As[row];
            float dot = 0.f;
            #pragma unroll 16
            for (int d = 0; d < DDIM; d += 4) {
                float4 c4 = *(const float4*)(cp + d);
                float4 a4 = *(const float4*)(ar + d);
                dot = __builtin_fmaf(a4.x, c4.x, dot);
                dot = __builtin_fmaf(a4.y, c4.y, dot);
                dot = __builtin_fmaf(a4.z, c4.z, dot);
                dot = __builtin_fmaf(a4.w, c4.w, dot);
            }
            float sx = __fsub_rn(__fmul_rn(2.f, dot), tabq[col].x);
            unsigned ub = __float_as_uint(sx);
            ub = (ub & 0x80000000u) ? ~ub : (ub | 0x80000000u);
            unsigned long long key = ((unsigned long long)ub << 10) | (unsigned)(1023 - col);
            atomicMax(&winner[row], key);
        };

        // ---- stage-wide maxes of ||eps_b|| and ||c|| ----
        float em = -INFINITY, cm = -INFINITY;
        #pragma unroll
        for (int j = 0; j < 4; ++j) {
            float4 t4 = tabq[tid + j * 256];
            em = fmaxf(em, t4.z);
            cm = fmaxf(cm, t4.w);
        }
        #pragma unroll
        for (int m = 1; m < 64; m <<= 1) {
            em = fmaxf(em, __shfl_xor(em, m, 64));
            cm = fmaxf(cm, __shfl_xor(cm, m, 64));
        }
        if (l == 0) { redE[w] = em; redC[w] = cm; }

        // ---- A fragments: residual -> i8 (register-resident all stage) ----
        FragI af[2][4];
        #pragma unroll
        for (int mt = 0; mt < 2; ++mt) {
            const float ma = fmaxf(__uint_as_float(maxa_s[mt * 16 + cl]), 1e-30f);
            const float sA = ma * (1.f / 127.f);
            const float invA = 127.f / ma;
            float e2 = 0.f;
            #pragma unroll
            for (int ks = 0; ks < 4; ++ks) {
                const float* ap = &As[mt * 16 + cl][ks * 64 + g * 16];
                af[mt][ks].u.x = pack8(*(const float4*)(ap + 0),  invA, sA, e2);
                af[mt][ks].u.y = pack8(*(const float4*)(ap + 4),  invA, sA, e2);
                af[mt][ks].u.z = pack8(*(const float4*)(ap + 8),  invA, sA, e2);
                af[mt][ks].u.w = pack8(*(const float4*)(ap + 12), invA, sA, e2);
            }
            e2 += __shfl_xor(e2, 16, 64);
            e2 += __shfl_xor(e2, 32, 64);
            if (w == 0 && g == 0) ean_s[mt * 16 + cl] = sqrtf(e2);
        }

        // per-lane 2*sA for this lane's 8 score rows (row = mt*16 + g*4 + jj)
        float sA2[2][4];
        #pragma unroll
        for (int mt = 0; mt < 2; ++mt)
            #pragma unroll
            for (int jj = 0; jj < 4; ++jj)
                sA2[mt][jj] = fmaxf(__uint_as_float(maxa_s[mt * 16 + g * 4 + jj]), 1e-30f)
                              * (2.f / 127.f);

        if (tid < RPB) { Mrow_s[tid] = -INFINITY; winner[tid] = 0ull; }
        if (tid == 0) { qcnt = 0; ovf = 0u; }
        barrier_lds();

        const float ebnMax = fmaxf(fmaxf(redE[0], redE[1]), fmaxf(redE[2], redE[3]));
        const float cnMax  = fmaxf(fmaxf(redC[0], redC[1]), fmaxf(redC[2], redC[3]));

        for (int quarter = 0; quarter < 4; ++quarter) {
            const int par = quarter & 1;
            float m_lane[2][4];
            #pragma unroll
            for (int mt = 0; mt < 2; ++mt)
                #pragma unroll
                for (int r = 0; r < 4; ++r) m_lane[mt][r] = -INFINITY;
            unsigned spack[4][2][2];   // 16 VGPRs, static-indexed

            #pragma unroll
            for (int cc = 0; cc < 4; ++cc) {
                const int ch = quarter * 4 + cc;
                uint4 (&cur)[4] = (cc & 1) ? bufB : bufA;
                uint4 (&nxt)[4] = (cc & 1) ? bufA : bufB;
                float4& tc = (cc & 1) ? tB : tA;
                float4& tn = (cc & 1) ? tA : tB;

                // prefetch next chunk (wraps to next stage's chunk 0)
                int pq = q, pch = ch + 1;
                if (ch == 15) { pq = (q < NQ - 1) ? q + 1 : q; pch = 0; }
                loadB(nxt, pq, pch);
                tn = loadT(pq, pch);
                __builtin_amdgcn_sched_barrier(0);   // pin: loads issue BEFORE MFMAs

                // ---- 8 MFMAs, 4 independent chains (ks even/odd x 2 tiles) ----
                i32x4 aE0 = {0,0,0,0}, aO0 = {0,0,0,0}, aE1 = {0,0,0,0}, aO1 = {0,0,0,0};
                #pragma unroll
                for (int ks = 0; ks < 4; ks += 2) {
                    FragI b0; b0.u = cur[ks];
                    FragI b1; b1.u = cur[ks + 1];
                    aE0 = __builtin_amdgcn_mfma_i32_16x16x64_i8(af[0][ks].i,     b0.i, aE0, 0, 0, 0);
                    aE1 = __builtin_amdgcn_mfma_i32_16x16x64_i8(af[1][ks].i,     b0.i, aE1, 0, 0, 0);
                    aO0 = __builtin_amdgcn_mfma_i32_16x16x64_i8(af[0][ks + 1].i, b1.i, aO0, 0, 0, 0);
                    aO1 = __builtin_amdgcn_mfma_i32_16x16x64_i8(af[1][ks + 1].i, b1.i, aO1, 0, 0, 0);
                }

                // ---- fold: s = sA*2sB*idot - cbsq; running max; truncate-pack ----
                const float cq = tc.x;
                const float sBc = tc.y;
                {
                    float s0 = __builtin_fmaf(sA2[0][0] * sBc, (float)(aE0[0] + aO0[0]), -cq);
                    float s1 = __builtin_fmaf(sA2[0][1] * sBc, (float)(aE0[1] + aO0[1]), -cq);
                    float s2 = __builtin_fmaf(sA2[0][2] * sBc, (float)(aE0[2] + aO0[2]), -cq);
                    float s3 = __builtin_fmaf(sA2[0][3] * sBc, (float)(aE0[3] + aO0[3]), -cq);
                    m_lane[0][0] = fmaxf(m_lane[0][0], s0);
                    m_lane[0][1] = fmaxf(m_lane[0][1], s1);
                    m_lane[0][2] = fmaxf(m_lane[0][2], s2);
                    m_lane[0][3] = fmaxf(m_lane[0][3], s3);
                    spack[cc][0][0] = (__float_as_uint(s1) & 0xFFFF0000u) | (__float_as_uint(s0) >> 16);
                    spack[cc][0][1] = (__float_as_uint(s3) & 0xFFFF0000u) | (__float_as_uint(s2) >> 16);
                }
                {
                    float s0 = __builtin_fmaf(sA2[1][0] * sBc, (float)(aE1[0] + aO1[0]), -cq);
                    float s1 = __builtin_fmaf(sA2[1][1] * sBc, (float)(aE1[1] + aO1[1]), -cq);
                    float s2 = __builtin_fmaf(sA2[1][2] * sBc, (float)(aE1[2] + aO1[2]), -cq);
                    float s3 = __builtin_fmaf(sA2[1][3] * sBc, (float)(aE1[3] + aO1[3]), -cq);
                    m_lane[1][0] = fmaxf(m_lane[1][0], s0);
                    m_lane[1][1] = fmaxf(m_lane[1][1], s1);
                    m_lane[1][2] = fmaxf(m_lane[1][2], s2);
                    m_lane[1][3] = fmaxf(m_lane[1][3], s3);
                    spack[cc][1][0] = (__float_as_uint(s1) & 0xFFFF0000u) | (__float_as_uint(s0) >> 16);
                    spack[cc][1][1] = (__float_as_uint(s3) & 0xFFFF0000u) | (__float_as_uint(s2) >> 16);
                }
            }

            // ---- publish per-wave row maxima (parity-buffered) ----
            #pragma unroll
            for (int m = 1; m <= 8; m <<= 1)
                #pragma unroll
                for (int mt = 0; mt < 2; ++mt)
                    #pragma unroll
                    for (int r = 0; r < 4; ++r)
                        m_lane[mt][r] = fmaxf(m_lane[mt][r], __shfl_xor(m_lane[mt][r], m, 64));
            if (cl == 0) {
                #pragma unroll
                for (int mt = 0; mt < 2; ++mt)
                    #pragma unroll
                    for (int r = 0; r < 4; ++r)
                        Mpart[par][w][mt * 16 + g * 4 + r] = m_lane[mt][r];
            }
            barrier_lds();

            // ---- per-lane thresholds: provable quantization margin ----
            // |s_true - s_est| <= 2(||r||ebn + ean||c|| + ean*ebn); margin = 2x
            float thrl[2][4];
            #pragma unroll
            for (int mt = 0; mt < 2; ++mt)
                #pragma unroll
                for (int jj = 0; jj < 4; ++jj) {
                    const int r = mt * 16 + g * 4 + jj;
                    float M = fmaxf(fmaxf(Mpart[par][0][r], Mpart[par][1][r]),
                                    fmaxf(Mpart[par][2][r], Mpart[par][3][r]));
                    float Mr = fmaxf(Mrow_s[r], M);
                    Mrow_s[r] = Mr;
                    float margin = 4.f * __builtin_fmaf(sqrtf(rsq[r]), ebnMax,
                                                        ean_s[r] * (cnMax + ebnMax))
                                 + 0.006f * fabsf(Mr) + 0.25f;
                    thrl[mt][jj] = Mr - margin;
                }

            // ---- scan quarter's scores, enqueue candidates ----
            #pragma unroll
            for (int cc = 0; cc < 4; ++cc) {
                const int colc = (quarter * 4 + cc) * 64 + w * 16 + cl;
                #pragma unroll
                for (int mt = 0; mt < 2; ++mt)
                    #pragma unroll
                    for (int pr = 0; pr < 2; ++pr) {
                        unsigned u = spack[cc][mt][pr];
                        float slo = __uint_as_float(u << 16);
                        float shi = __uint_as_float(u & 0xFFFF0000u);
                        if (slo >= thrl[mt][pr * 2]) {
                            const int row = mt * 16 + g * 4 + pr * 2;
                            int p = atomicAdd(&qcnt, 1);
                            if (__builtin_expect(p < QMAX, 1)) qlist[p] = (row << 10) | colc;
                            else atomicOr(&ovf, 1u << row);
                        }
                        if (shi >= thrl[mt][pr * 2 + 1]) {
                            const int row = mt * 16 + g * 4 + pr * 2 + 1;
                            int p = atomicAdd(&qcnt, 1);
                            if (__builtin_expect(p < QMAX, 1)) qlist[p] = (row << 10) | colc;
                            else atomicOr(&ovf, 1u << row);
                        }
                    }
            }
        }
        barrier_lds();

        // ---- exact rescore (sequential-K fp32, reference ordering) ----
        {
            int nc = qcnt < QMAX ? qcnt : QMAX;
            for (int i = tid; i < nc; i += 256) {
                const int rc = qlist[i];
                exact_score(rc >> 10, rc & 1023);
            }
            // repair pass: rows whose candidates overflowed -> full rescan.
            if (__builtin_expect(ovf != 0u, 0)) {
                unsigned om = ovf;
                while (om) {
                    const int row = __ffs(om) - 1;
                    om &= om - 1;
                    for (int c = tid; c < KBINS; c += 256) exact_score(row, c);
                }
            }
        }
        barrier_lds();
        if (tid < RPB) {
            int col = 1023 - (int)(winner[tid] & 1023ull);
            idxs[tid] = col;
            codes_f[(size_t)q * NROWS + r0 + tid] = (float)col;
            rsq[tid] = 0.f;
            maxa_s[tid] = 0u;
        }
        barrier_lds();

        // ---- update: tmp=c-r; qst=r+tmp; r=r-qst (reference rounding) ----
        {
            const int row = tid & 31, d0 = (tid >> 5) * 32;
            const float* crow = cbq + (size_t)idxs[row] * DDIM + d0;
            float* arow = &As[row][d0];
            float lp = 0.f, pr = 0.f, ma = 0.f;
            #pragma unroll
            for (int u = 0; u < 32; u += 4) {
                const float4 c4 = *(const float4*)(crow + u);
                const float4 a4 = *(const float4*)(arow + u);
                const float cv[4] = { c4.x, c4.y, c4.z, c4.w };
                const float rv[4] = { a4.x, a4.y, a4.z, a4.w };
                float rn[4];
                #pragma unroll
                for (int v = 0; v < 4; ++v) {
                    const float tmp = __fsub_rn(cv[v], rv[v]);
                    const float qs  = __fadd_rn(rv[v], tmp);
                    rn[v] = __fsub_rn(rv[v], qs);
                    lp = __builtin_fmaf(tmp, tmp, lp);
                    pr = __builtin_fmaf(rn[v], rn[v], pr);
                    ma = fmaxf(ma, fabsf(rn[v]));
                }
                float4 o4; o4.x = rn[0]; o4.y = rn[1]; o4.z = rn[2]; o4.w = rn[3];
                *(float4*)(arow + u) = o4;
            }
            #pragma unroll
            for (int m = 1; m < 64; m <<= 1) lp += __shfl_xor(lp, m, 64);
            if (l == 0) atomicAdd(&loss[q], lp);
            atomicAdd(&rsq[row], pr);
            atomicMax(&maxa_s[row], __float_as_uint(ma));
        }
        barrier_lds();
    }

    // ---- quantized output: x - final residual (telescoped) ----
    {
        const int row = tid & 31, dg = tid >> 5;
        const int n = r0 + row, b = n / TLEN, t = n % TLEN;
        const float* xp = x + (size_t)b * (DDIM * TLEN) + t;
        float* op = out + (size_t)b * (DDIM * TLEN) + t;
        #pragma unroll
        for (int u = 0; u < 32; ++u) {
            const int d = dg * 32 + u;
            op[(size_t)d * TLEN] = __fsub_rn(xp[(size_t)d * TLEN], As[row][d]);
        }
    }
}

// ---------------------------------------------------------------------------
// Kernel 3: penalty = mean over stages of (loss_q / (N*D))
// ---------------------------------------------------------------------------
__global__ void finalize_kernel(const float* __restrict__ loss, float* __restrict__ out) {
    if (threadIdx.x == 0 && blockIdx.x == 0) {
        float s = 0.f;
        for (int q = 0; q < NQ; ++q) s += loss[q] / (float)(NROWS * DDIM);
        out[(size_t)NBATCH * DDIM * TLEN + (size_t)NQ * NROWS] = s / (float)NQ;
    }
}

extern "C" void kernel_launch(void* const* d_in, const int* in_sizes, int n_in,
                              void* d_out, int out_size, void* d_ws, size_t ws_size,
                              hipStream_t stream) {
    const float* x  = (const float*)d_in[0];
    const float* cb = (const float*)d_in[1];
    float* out  = (float*)d_out;
    float* ws   = (float*)d_ws;
    float4* tab = (float4*)ws;                        // 8192 float4 = 131072 B
    float* loss = ws + 4 * NQ * KBINS;                // 8 floats @ 131072 B
    uint4* cbbf = (uint4*)((char*)d_ws + 131104);     // 131072 uint4 = 2 MB
    const bool wsbf = ws_size >= (size_t)(131104 + 131072 * 16);

    hipLaunchKernelGGL(table_kernel, dim3((NQ * KBINS) / 256), dim3(256), 0, stream, cb, ws);
    if (wsbf) {
        hipLaunchKernelGGL(precvt8_kernel, dim3(131072 / 256), dim3(256), 0, stream,
                           cb, tab, cbbf);
        hipLaunchKernelGGL((rvq_kernel<true>), dim3(NROWS / RPB), dim3(256), 0, stream,
                           x, cb, cbbf, tab, loss, out);
    } else {
        hipLaunchKernelGGL((rvq_kernel<false>), dim3(NROWS / RPB), dim3(256), 0, stream,
                           x, cb, cbbf, tab, loss, out);
    }
    hipLaunchKernelGGL(finalize_kernel, dim3(1), dim3(64), 0, stream, loss, out);
}

// Round 5
// 460.702 us; speedup vs baseline: 17.4171x; 17.4171x over previous
//
#include <hip/hip_runtime.h>
#include <math.h>

#define NBATCH 16
#define DDIM   256
#define TLEN   1500
#define NROWS  (NBATCH * TLEN)     // 24000
#define KBINS  1024
#define NQ     8
#define RPB    32                  // rows per block
#define QMAX   384

typedef float f32x4 __attribute__((ext_vector_type(4)));
typedef int   i32x4 __attribute__((ext_vector_type(4)));
union FragI { uint4 u; i32x4 i; };

// LDS-only barrier: waits ds ops, does NOT drain vmcnt -> global prefetch
// stays in flight across phase boundaries. All inter-wave comms here are LDS.
__device__ __forceinline__ void barrier_lds() {
    __builtin_amdgcn_sched_barrier(0);
    asm volatile("s_waitcnt lgkmcnt(0)" ::: "memory");
    __builtin_amdgcn_s_barrier();
    __builtin_amdgcn_sched_barrier(0);
}

// quantize 4 floats to 4 i8 (round-nearest-even), accumulate exact eps^2
__device__ __forceinline__ unsigned pack8(float4 v, float inv, float s, float& e2) {
    float q0 = rintf(v.x * inv), q1 = rintf(v.y * inv);
    float q2 = rintf(v.z * inv), q3 = rintf(v.w * inv);
    float e0 = __builtin_fmaf(-s, q0, v.x), e1 = __builtin_fmaf(-s, q1, v.y);
    float f2 = __builtin_fmaf(-s, q2, v.z), f3 = __builtin_fmaf(-s, q3, v.w);
    e2 += e0 * e0 + e1 * e1 + f2 * f2 + f3 * f3;
    return ((unsigned)((int)q0 & 255)) | (((unsigned)((int)q1 & 255)) << 8)
         | (((unsigned)((int)q2 & 255)) << 16) | (((unsigned)((int)q3 & 255)) << 24);
}

// ---------------------------------------------------------------------------
// Kernel 1: per-col table: (cbsq numpy-pairwise, sB, ||eps_b||, ||c||) + zero losses
// ---------------------------------------------------------------------------
__global__ __launch_bounds__(256) void table_kernel(const float* __restrict__ cb,
                                                    float* __restrict__ ws) {
    const int k = blockIdx.x * 256 + threadIdx.x;      // 0..8191
    if (blockIdx.x == 0 && threadIdx.x < NQ) ws[4 * NQ * KBINS + threadIdx.x] = 0.f;
    if (k >= NQ * KBINS) return;
    const float* p = cb + (size_t)k * DDIM;
    // numpy-pairwise sum(c*c) -- EXACT structure as the passing kernel
    float total = 0.f;
    #pragma unroll
    for (int h = 0; h < 2; ++h) {
        const float* ph = p + h * 128;
        float r[8];
        #pragma unroll
        for (int j = 0; j < 8; ++j) { float v = ph[j]; r[j] = __fmul_rn(v, v); }
        for (int i = 8; i < 128; i += 8) {
            #pragma unroll
            for (int j = 0; j < 8; ++j) {
                float v = ph[i + j];
                r[j] = __fadd_rn(r[j], __fmul_rn(v, v));
            }
        }
        float s = __fadd_rn(__fadd_rn(__fadd_rn(r[0], r[1]), __fadd_rn(r[2], r[3])),
                            __fadd_rn(__fadd_rn(r[4], r[5]), __fadd_rn(r[6], r[7])));
        total = __fadd_rn(total, s);
    }
    // maxabs -> sB; exact quantization error norm
    float ma = 0.f;
    for (int i = 0; i < DDIM; i += 4) {
        float4 v = *(const float4*)(p + i);
        ma = fmaxf(ma, fmaxf(fmaxf(fabsf(v.x), fabsf(v.y)), fmaxf(fabsf(v.z), fabsf(v.w))));
    }
    const float sB = fmaxf(ma, 1e-30f) * (1.f / 127.f);
    const float invB = 1.f / sB;
    float es = 0.f;
    for (int i = 0; i < DDIM; i += 4) {
        float4 v = *(const float4*)(p + i);
        (void)pack8(v, invB, sB, es);
    }
    float4 t;
    t.x = total; t.y = sB; t.z = sqrtf(es); t.w = sqrtf(total);
    ((float4*)ws)[k] = t;
}

// ---------------------------------------------------------------------------
// Kernel 1b: pre-quantize codebooks fp32 -> i8 in per-lane MFMA fragment order
// uint4 index J = ((((q*16+ch)*4 + w)*4 + ks)*64 + l); byte p of lane l:
// col = ch*64 + w*16 + (l&15), k = ks*64 + (l>>4)*16 + p  (A uses same k map;
// any k-permutation applied to BOTH operands leaves the dot invariant)
// ---------------------------------------------------------------------------
__global__ __launch_bounds__(256) void precvt8_kernel(const float* __restrict__ cb,
                                                      const float4* __restrict__ tab,
                                                      uint4* __restrict__ cbbf) {
    const int j = blockIdx.x * 256 + threadIdx.x;      // < 131072
    const int l  = j & 63;
    const int ks = (j >> 6) & 3;
    const int w  = (j >> 8) & 3;
    const int ch = (j >> 10) & 15;
    const int q  = j >> 14;
    const int C  = ch * 64 + w * 16 + (l & 15);
    const int g  = l >> 4;
    const float* src = cb + ((size_t)q * KBINS + C) * DDIM + ks * 64 + g * 16;
    const float sB = tab[q * KBINS + C].y;
    const float invB = 1.f / sB;
    float dummy = 0.f;
    uint4 o;
    o.x = pack8(*(const float4*)(src + 0),  invB, sB, dummy);
    o.y = pack8(*(const float4*)(src + 4),  invB, sB, dummy);
    o.z = pack8(*(const float4*)(src + 8),  invB, sB, dummy);
    o.w = pack8(*(const float4*)(src + 12), invB, sB, dummy);
    cbbf[j] = o;
}

// ---------------------------------------------------------------------------
// Kernel 2: residual VQ. i8-MFMA screening (exact int dot), statistical
// 16-sigma quantization margin (err = -2(r.eb + ea.c); sigma1=||r||ebn/sqrtD,
// sigma2=||c||ean/sqrtD; margin = 16(s1+s2) >= 11 sigma of actual error),
// register-double-buffered B, LDS-only barriers, global cross-wave row-max
// thresholds, exact fp32 rescoring + overflow repair pass (exact any qcnt).
// launch_bounds(256,2): proven spill-free budget; i8 demand ~150 regs ->
// hardware fits 3 blocks/CU (LDS 36.9KB would allow 4).
// ---------------------------------------------------------------------------
template<bool WSCB>
__global__ __launch_bounds__(256, 2) void rvq_kernel(const float* __restrict__ x,
                                                     const float* __restrict__ cb,
                                                     const uint4* __restrict__ cbbf,
                                                     const float4* __restrict__ tab,
                                                     float* __restrict__ loss,
                                                     float* __restrict__ out) {
    __shared__ __align__(16) float As[RPB][260];       // residual fp32 (33.3KB)
    __shared__ float rsq[RPB];
    __shared__ unsigned maxa_s[RPB];                   // row maxabs (fabs bits)
    __shared__ float ean_s[RPB];                       // row ||eps_a||
    __shared__ float Mrow_s[RPB];
    __shared__ float Mpart[2][4][RPB];                 // parity-buffered (1KB)
    __shared__ unsigned long long winner[RPB];
    __shared__ int   idxs[RPB];
    __shared__ int   qlist[QMAX];                      // 1.5KB
    __shared__ int   qcnt;
    __shared__ unsigned ovf;                           // rows whose cands overflowed
    __shared__ float redE[4], redC[4];

    const int tid = threadIdx.x;
    const int r0  = blockIdx.x * RPB;
    const int w   = tid >> 6;          // wave 0..3
    const int l   = tid & 63;
    const int cl  = l & 15;
    const int g   = l >> 4;            // 0..3

    if (tid < RPB) { rsq[tid] = 0.f; maxa_s[tid] = 0u; }
    barrier_lds();

    // ---- load x (B,D,T) transposed into As[row][d]; ||r||^2 and maxabs ----
    {
        const int row = tid & 31, dg = tid >> 5;
        const int n = r0 + row, b = n / TLEN, t = n % TLEN;
        const float* xp = x + (size_t)b * (DDIM * TLEN) + t;
        float pr = 0.f, ma = 0.f;
        #pragma unroll
        for (int dd = 0; dd < DDIM; dd += 8) {
            float v = xp[(size_t)(dd + dg) * TLEN];
            As[row][dd + dg] = v;
            pr = __builtin_fmaf(v, v, pr);
            ma = fmaxf(ma, fabsf(v));
        }
        atomicAdd(&rsq[row], pr);
        atomicMax(&maxa_s[row], __float_as_uint(ma));
    }
    barrier_lds();

    float* codes_f = out + (size_t)NBATCH * DDIM * TLEN;

    // B-fragment loader: 4 coalesced dwordx4 per chunk (i8, K=64 each)
    auto loadB = [&](uint4 (&buf)[4], int q_, int ch_) {
        if constexpr (WSCB) {
            const uint4* p = cbbf + ((size_t)((q_ * 16 + ch_) * 4 + w) * 4) * 64 + l;
            #pragma unroll
            for (int ks = 0; ks < 4; ++ks) buf[ks] = p[ks * 64];
        } else {
            const int C = ch_ * 64 + w * 16 + cl;
            const float* cp = cb + ((size_t)q_ * KBINS + C) * DDIM;
            const float sB = tab[q_ * KBINS + C].y;
            const float invB = 1.f / sB;
            float dmy = 0.f;
            #pragma unroll
            for (int ks = 0; ks < 4; ++ks) {
                const int d0 = ks * 64 + g * 16;
                buf[ks].x = pack8(*(const float4*)(cp + d0 + 0),  invB, sB, dmy);
                buf[ks].y = pack8(*(const float4*)(cp + d0 + 4),  invB, sB, dmy);
                buf[ks].z = pack8(*(const float4*)(cp + d0 + 8),  invB, sB, dmy);
                buf[ks].w = pack8(*(const float4*)(cp + d0 + 12), invB, sB, dmy);
            }
        }
    };
    auto loadT = [&](int q_, int ch_) -> float4 {
        return tab[q_ * KBINS + ch_ * 64 + w * 16 + cl];
    };

    uint4 bufA[4], bufB[4];
    float4 tA, tB;
    loadB(bufA, 0, 0);                 // prologue: stage 0 chunk 0 in flight
    tA = loadT(0, 0);
    __builtin_amdgcn_sched_barrier(0);

    for (int q = 0; q < NQ; ++q) {
        const float* cbq = cb + (size_t)q * (KBINS * DDIM);
        const float4* tabq = tab + (size_t)q * KBINS;

        // exact fp32 score of (row,col) -> tournament key -> atomicMax winner
        auto exact_score = [&](int row, int col) {
            const float* cp = cbq + (size_t)col * DDIM;
            const float* ar = As[row];
            float dot = 0.f;
            #pragma unroll 16
            for (int d = 0; d < DDIM; d += 4) {
                float4 c4 = *(const float4*)(cp + d);
                float4 a4 = *(const float4*)(ar + d);
                dot = __builtin_fmaf(a4.x, c4.x, dot);
                dot = __builtin_fmaf(a4.y, c4.y, dot);
                dot = __builtin_fmaf(a4.z, c4.z, dot);
                dot = __builtin_fmaf(a4.w, c4.w, dot);
            }
            float sx = __fsub_rn(__fmul_rn(2.f, dot), tabq[col].x);
            unsigned ub = __float_as_uint(sx);
            ub = (ub & 0x80000000u) ? ~ub : (ub | 0x80000000u);
            unsigned long long key = ((unsigned long long)ub << 10) | (unsigned)(1023 - col);
            atomicMax(&winner[row], key);
        };

        // ---- stage-wide maxes of ||eps_b|| and ||c|| ----
        float em = -INFINITY, cm = -INFINITY;
        #pragma unroll
        for (int j = 0; j < 4; ++j) {
            float4 t4 = tabq[tid + j * 256];
            em = fmaxf(em, t4.z);
            cm = fmaxf(cm, t4.w);
        }
        #pragma unroll
        for (int m = 1; m < 64; m <<= 1) {
            em = fmaxf(em, __shfl_xor(em, m, 64));
            cm = fmaxf(cm, __shfl_xor(cm, m, 64));
        }
        if (l == 0) { redE[w] = em; redC[w] = cm; }

        // ---- A fragments: residual -> i8 (register-resident all stage) ----
        FragI af[2][4];
        #pragma unroll
        for (int mt = 0; mt < 2; ++mt) {
            const float ma = fmaxf(__uint_as_float(maxa_s[mt * 16 + cl]), 1e-30f);
            const float sA = ma * (1.f / 127.f);
            const float invA = 127.f / ma;
            float e2 = 0.f;
            #pragma unroll
            for (int ks = 0; ks < 4; ++ks) {
                const float* ap = &As[mt * 16 + cl][ks * 64 + g * 16];
                af[mt][ks].u.x = pack8(*(const float4*)(ap + 0),  invA, sA, e2);
                af[mt][ks].u.y = pack8(*(const float4*)(ap + 4),  invA, sA, e2);
                af[mt][ks].u.z = pack8(*(const float4*)(ap + 8),  invA, sA, e2);
                af[mt][ks].u.w = pack8(*(const float4*)(ap + 12), invA, sA, e2);
            }
            e2 += __shfl_xor(e2, 16, 64);
            e2 += __shfl_xor(e2, 32, 64);
            if (w == 0 && g == 0) ean_s[mt * 16 + cl] = sqrtf(e2);
        }

        // per-lane 2*sA for this lane's 8 score rows (row = mt*16 + g*4 + jj)
        float sA2[2][4];
        #pragma unroll
        for (int mt = 0; mt < 2; ++mt)
            #pragma unroll
            for (int jj = 0; jj < 4; ++jj)
                sA2[mt][jj] = fmaxf(__uint_as_float(maxa_s[mt * 16 + g * 4 + jj]), 1e-30f)
                              * (2.f / 127.f);

        if (tid < RPB) { Mrow_s[tid] = -INFINITY; winner[tid] = 0ull; }
        if (tid == 0) { qcnt = 0; ovf = 0u; }
        barrier_lds();

        const float ebnMax = fmaxf(fmaxf(redE[0], redE[1]), fmaxf(redE[2], redE[3]));
        const float cnMax  = fmaxf(fmaxf(redC[0], redC[1]), fmaxf(redC[2], redC[3]));

        for (int quarter = 0; quarter < 4; ++quarter) {
            const int par = quarter & 1;
            float m_lane[2][4];
            #pragma unroll
            for (int mt = 0; mt < 2; ++mt)
                #pragma unroll
                for (int r = 0; r < 4; ++r) m_lane[mt][r] = -INFINITY;
            unsigned spack[4][2][2];   // 16 VGPRs, static-indexed

            #pragma unroll
            for (int cc = 0; cc < 4; ++cc) {
                const int ch = quarter * 4 + cc;
                uint4 (&cur)[4] = (cc & 1) ? bufB : bufA;
                uint4 (&nxt)[4] = (cc & 1) ? bufA : bufB;
                float4& tc = (cc & 1) ? tB : tA;
                float4& tn = (cc & 1) ? tA : tB;

                // prefetch next chunk (wraps to next stage's chunk 0)
                int pq = q, pch = ch + 1;
                if (ch == 15) { pq = (q < NQ - 1) ? q + 1 : q; pch = 0; }
                loadB(nxt, pq, pch);
                tn = loadT(pq, pch);
                __builtin_amdgcn_sched_barrier(0);   // pin: loads issue BEFORE MFMAs

                // ---- 8 MFMAs, 4 independent chains (ks even/odd x 2 tiles) ----
                i32x4 aE0 = {0,0,0,0}, aO0 = {0,0,0,0}, aE1 = {0,0,0,0}, aO1 = {0,0,0,0};
                #pragma unroll
                for (int ks = 0; ks < 4; ks += 2) {
                    FragI b0; b0.u = cur[ks];
                    FragI b1; b1.u = cur[ks + 1];
                    aE0 = __builtin_amdgcn_mfma_i32_16x16x64_i8(af[0][ks].i,     b0.i, aE0, 0, 0, 0);
                    aE1 = __builtin_amdgcn_mfma_i32_16x16x64_i8(af[1][ks].i,     b0.i, aE1, 0, 0, 0);
                    aO0 = __builtin_amdgcn_mfma_i32_16x16x64_i8(af[0][ks + 1].i, b1.i, aO0, 0, 0, 0);
                    aO1 = __builtin_amdgcn_mfma_i32_16x16x64_i8(af[1][ks + 1].i, b1.i, aO1, 0, 0, 0);
                }

                // ---- fold: s = sA*2sB*idot - cbsq; running max; truncate-pack ----
                const float cq = tc.x;
                const float sBc = tc.y;
                {
                    float s0 = __builtin_fmaf(sA2[0][0] * sBc, (float)(aE0[0] + aO0[0]), -cq);
                    float s1 = __builtin_fmaf(sA2[0][1] * sBc, (float)(aE0[1] + aO0[1]), -cq);
                    float s2 = __builtin_fmaf(sA2[0][2] * sBc, (float)(aE0[2] + aO0[2]), -cq);
                    float s3 = __builtin_fmaf(sA2[0][3] * sBc, (float)(aE0[3] + aO0[3]), -cq);
                    m_lane[0][0] = fmaxf(m_lane[0][0], s0);
                    m_lane[0][1] = fmaxf(m_lane[0][1], s1);
                    m_lane[0][2] = fmaxf(m_lane[0][2], s2);
                    m_lane[0][3] = fmaxf(m_lane[0][3], s3);
                    spack[cc][0][0] = (__float_as_uint(s1) & 0xFFFF0000u) | (__float_as_uint(s0) >> 16);
                    spack[cc][0][1] = (__float_as_uint(s3) & 0xFFFF0000u) | (__float_as_uint(s2) >> 16);
                }
                {
                    float s0 = __builtin_fmaf(sA2[1][0] * sBc, (float)(aE1[0] + aO1[0]), -cq);
                    float s1 = __builtin_fmaf(sA2[1][1] * sBc, (float)(aE1[1] + aO1[1]), -cq);
                    float s2 = __builtin_fmaf(sA2[1][2] * sBc, (float)(aE1[2] + aO1[2]), -cq);
                    float s3 = __builtin_fmaf(sA2[1][3] * sBc, (float)(aE1[3] + aO1[3]), -cq);
                    m_lane[1][0] = fmaxf(m_lane[1][0], s0);
                    m_lane[1][1] = fmaxf(m_lane[1][1], s1);
                    m_lane[1][2] = fmaxf(m_lane[1][2], s2);
                    m_lane[1][3] = fmaxf(m_lane[1][3], s3);
                    spack[cc][1][0] = (__float_as_uint(s1) & 0xFFFF0000u) | (__float_as_uint(s0) >> 16);
                    spack[cc][1][1] = (__float_as_uint(s3) & 0xFFFF0000u) | (__float_as_uint(s2) >> 16);
                }
            }

            // ---- publish per-wave row maxima (parity-buffered) ----
            #pragma unroll
            for (int m = 1; m <= 8; m <<= 1)
                #pragma unroll
                for (int mt = 0; mt < 2; ++mt)
                    #pragma unroll
                    for (int r = 0; r < 4; ++r)
                        m_lane[mt][r] = fmaxf(m_lane[mt][r], __shfl_xor(m_lane[mt][r], m, 64));
            if (cl == 0) {
                #pragma unroll
                for (int mt = 0; mt < 2; ++mt)
                    #pragma unroll
                    for (int r = 0; r < 4; ++r)
                        Mpart[par][w][mt * 16 + g * 4 + r] = m_lane[mt][r];
            }
            barrier_lds();

            // ---- per-lane thresholds: 16-sigma statistical quant margin ----
            // err = -2(r.eb + ea.c); margin = (||r||ebnMax + cnMax*ean)
            //     = 16*(sigma1+sigma2)  (sqrtD=16)  >= 11 sigma of |err| sum
            float thrl[2][4];
            #pragma unroll
            for (int mt = 0; mt < 2; ++mt)
                #pragma unroll
                for (int jj = 0; jj < 4; ++jj) {
                    const int r = mt * 16 + g * 4 + jj;
                    float M = fmaxf(fmaxf(Mpart[par][0][r], Mpart[par][1][r]),
                                    fmaxf(Mpart[par][2][r], Mpart[par][3][r]));
                    float Mr = fmaxf(Mrow_s[r], M);
                    Mrow_s[r] = Mr;
                    float margin = __builtin_fmaf(sqrtf(rsq[r]), ebnMax,
                                                  ean_s[r] * cnMax)
                                 + 0.006f * fabsf(Mr) + 0.25f;
                    thrl[mt][jj] = Mr - margin;
                }

            // ---- scan quarter's scores, enqueue candidates ----
            #pragma unroll
            for (int cc = 0; cc < 4; ++cc) {
                const int colc = (quarter * 4 + cc) * 64 + w * 16 + cl;
                #pragma unroll
                for (int mt = 0; mt < 2; ++mt)
                    #pragma unroll
                    for (int pr = 0; pr < 2; ++pr) {
                        unsigned u = spack[cc][mt][pr];
                        float slo = __uint_as_float(u << 16);
                        float shi = __uint_as_float(u & 0xFFFF0000u);
                        if (slo >= thrl[mt][pr * 2]) {
                            const int row = mt * 16 + g * 4 + pr * 2;
                            int p = atomicAdd(&qcnt, 1);
                            if (__builtin_expect(p < QMAX, 1)) qlist[p] = (row << 10) | colc;
                            else atomicOr(&ovf, 1u << row);
                        }
                        if (shi >= thrl[mt][pr * 2 + 1]) {
                            const int row = mt * 16 + g * 4 + pr * 2 + 1;
                            int p = atomicAdd(&qcnt, 1);
                            if (__builtin_expect(p < QMAX, 1)) qlist[p] = (row << 10) | colc;
                            else atomicOr(&ovf, 1u << row);
                        }
                    }
            }
        }
        barrier_lds();

        // ---- exact rescore (sequential-K fp32, reference ordering) ----
        {
            int nc = qcnt < QMAX ? qcnt : QMAX;
            for (int i = tid; i < nc; i += 256) {
                const int rc = qlist[i];
                exact_score(rc >> 10, rc & 1023);
            }
            // repair pass: rows whose candidates overflowed -> full rescan.
            if (__builtin_expect(ovf != 0u, 0)) {
                unsigned om = ovf;
                while (om) {
                    const int row = __ffs(om) - 1;
                    om &= om - 1;
                    for (int c = tid; c < KBINS; c += 256) exact_score(row, c);
                }
            }
        }
        barrier_lds();
        if (tid < RPB) {
            int col = 1023 - (int)(winner[tid] & 1023ull);
            idxs[tid] = col;
            codes_f[(size_t)q * NROWS + r0 + tid] = (float)col;
            rsq[tid] = 0.f;
            maxa_s[tid] = 0u;
        }
        barrier_lds();

        // ---- update: tmp=c-r; qst=r+tmp; r=r-qst (reference rounding) ----
        {
            const int row = tid & 31, d0 = (tid >> 5) * 32;
            const float* crow = cbq + (size_t)idxs[row] * DDIM + d0;
            float* arow = &As[row][d0];
            float lp = 0.f, pr = 0.f, ma = 0.f;
            #pragma unroll
            for (int u = 0; u < 32; u += 4) {
                const float4 c4 = *(const float4*)(crow + u);
                const float4 a4 = *(const float4*)(arow + u);
                const float cv[4] = { c4.x, c4.y, c4.z, c4.w };
                const float rv[4] = { a4.x, a4.y, a4.z, a4.w };
                float rn[4];
                #pragma unroll
                for (int v = 0; v < 4; ++v) {
                    const float tmp = __fsub_rn(cv[v], rv[v]);
                    const float qs  = __fadd_rn(rv[v], tmp);
                    rn[v] = __fsub_rn(rv[v], qs);
                    lp = __builtin_fmaf(tmp, tmp, lp);
                    pr = __builtin_fmaf(rn[v], rn[v], pr);
                    ma = fmaxf(ma, fabsf(rn[v]));
                }
                float4 o4; o4.x = rn[0]; o4.y = rn[1]; o4.z = rn[2]; o4.w = rn[3];
                *(float4*)(arow + u) = o4;
            }
            #pragma unroll
            for (int m = 1; m < 64; m <<= 1) lp += __shfl_xor(lp, m, 64);
            if (l == 0) atomicAdd(&loss[q], lp);
            atomicAdd(&rsq[row], pr);
            atomicMax(&maxa_s[row], __float_as_uint(ma));
        }
        barrier_lds();
    }

    // ---- quantized output: x - final residual (telescoped) ----
    {
        const int row = tid & 31, dg = tid >> 5;
        const int n = r0 + row, b = n / TLEN, t = n % TLEN;
        const float* xp = x + (size_t)b * (DDIM * TLEN) + t;
        float* op = out + (size_t)b * (DDIM * TLEN) + t;
        #pragma unroll
        for (int u = 0; u < 32; ++u) {
            const int d = dg * 32 + u;
            op[(size_t)d * TLEN] = __fsub_rn(xp[(size_t)d * TLEN], As[row][d]);
        }
    }
}

// ---------------------------------------------------------------------------
// Kernel 3: penalty = mean over stages of (loss_q / (N*D))
// ---------------------------------------------------------------------------
__global__ void finalize_kernel(const float* __restrict__ loss, float* __restrict__ out) {
    if (threadIdx.x == 0 && blockIdx.x == 0) {
        float s = 0.f;
        for (int q = 0; q < NQ; ++q) s += loss[q] / (float)(NROWS * DDIM);
        out[(size_t)NBATCH * DDIM * TLEN + (size_t)NQ * NROWS] = s / (float)NQ;
    }
}

extern "C" void kernel_launch(void* const* d_in, const int* in_sizes, int n_in,
                              void* d_out, int out_size, void* d_ws, size_t ws_size,
                              hipStream_t stream) {
    const float* x  = (const float*)d_in[0];
    const float* cb = (const float*)d_in[1];
    float* out  = (float*)d_out;
    float* ws   = (float*)d_ws;
    float4* tab = (float4*)ws;                        // 8192 float4 = 131072 B
    float* loss = ws + 4 * NQ * KBINS;                // 8 floats @ 131072 B
    uint4* cbbf = (uint4*)((char*)d_ws + 131104);     // 131072 uint4 = 2 MB
    const bool wsbf = ws_size >= (size_t)(131104 + 131072 * 16);

    hipLaunchKernelGGL(table_kernel, dim3((NQ * KBINS) / 256), dim3(256), 0, stream, cb, ws);
    if (wsbf) {
        hipLaunchKernelGGL(precvt8_kernel, dim3(131072 / 256), dim3(256), 0, stream,
                           cb, tab, cbbf);
        hipLaunchKernelGGL((rvq_kernel<true>), dim3(NROWS / RPB), dim3(256), 0, stream,
                           x, cb, cbbf, tab, loss, out);
    } else {
        hipLaunchKernelGGL((rvq_kernel<false>), dim3(NROWS / RPB), dim3(256), 0, stream,
                           x, cb, cbbf, tab, loss, out);
    }
    hipLaunchKernelGGL(finalize_kernel, dim3(1), dim3(64), 0, stream, loss, out);
}